// Round 11
// baseline (1301.071 us; speedup 1.0000x reference)
//
#include <hip/hip_runtime.h>
#include <math.h>

#define D_DIM 128
#define H_DIM 128
#define SQRT_H_INV 0.08838834764831845f
// packed B panel columns: [wq 512 | wk 512 | wv 512 | wskip 128 | g0 512 | g1 512 | wih-igo 384]
#define BCOL_QKV 0
#define BCOL_G0 1664
#define BCOL_G1 2176
#define BCOL_W  2688
#define BCOL_TOT 3072

typedef unsigned short u16;
typedef unsigned int u32;
typedef unsigned short ushort8v __attribute__((ext_vector_type(8)));
typedef unsigned int u32x4 __attribute__((ext_vector_type(4)));
typedef __bf16 bf16x8 __attribute__((ext_vector_type(8)));
typedef float f32x4 __attribute__((ext_vector_type(4)));
typedef float f32x2 __attribute__((ext_vector_type(2)));

// Fragment-major (FM) split layout for a [rows][128] matrix:
//   elem (row,k): g=k>>3, e=k&7
//   off = (row>>4)*2048 + g*128 + (row&15)*8 + e

__device__ __forceinline__ float grp16_sum(float v) {
  v += __shfl_xor(v, 1);
  v += __shfl_xor(v, 2);
  v += __shfl_xor(v, 4);
  v += __shfl_xor(v, 8);
  return v;
}

__device__ __forceinline__ void split_bf16(float x, u16& h, u16& l) {
  __bf16 hb = (__bf16)x;
  float rm = x - (float)hb;
  __bf16 lb = (__bf16)rm;
  h = __builtin_bit_cast(u16, hb);
  l = __builtin_bit_cast(u16, lb);
}

// packed bf16x2 pair -> f32x2 (2 bit-ops)
__device__ __forceinline__ f32x2 cvt2(u32 v) {
  f32x2 r;
  r[0] = __builtin_bit_cast(float, v << 16);
  r[1] = __builtin_bit_cast(float, v & 0xffff0000u);
  return r;
}

// 8-element bf16 dot via v_dot2_f32_bf16 (f32 accumulate)
__device__ __forceinline__ float qk_dot(const u32x4 q, const u32x4 k) {
  float p = 0.f;
  asm("v_dot2_f32_bf16 %0, %1, %2, %0" : "+v"(p) : "v"(q[0]), "v"(k[0]));
  asm("v_dot2_f32_bf16 %0, %1, %2, %0" : "+v"(p) : "v"(q[1]), "v"(k[1]));
  asm("v_dot2_f32_bf16 %0, %1, %2, %0" : "+v"(p) : "v"(q[2]), "v"(k[2]));
  asm("v_dot2_f32_bf16 %0, %1, %2, %0" : "+v"(p) : "v"(q[3]), "v"(k[3]));
  return p;
}

// wave-level work stealing: lane 0 grabs, broadcast to wave
__device__ __forceinline__ int steal(int* ctr, int lane) {
  int n = 0;
  if (lane == 0) n = atomicAdd(ctr, 1);
  return __shfl(n, 0);
}

// ---------------------------------------------------------------------------
__global__ __launch_bounds__(128) void k_event(
    const float* __restrict__ ef, int EV,
    const float* __restrict__ w1, const float* __restrict__ b1,
    const float* __restrict__ g1, const float* __restrict__ bt1,
    const float* __restrict__ w2, const float* __restrict__ b2,
    const float* __restrict__ g2, const float* __restrict__ bt2,
    const float* __restrict__ ett, const int* __restrict__ etid,
    const float* __restrict__ inten, int K,
    float* __restrict__ e_out)
{
  __shared__ float sh[H_DIM];
  __shared__ float red[H_DIM];
  const int t = threadIdx.x;

  float acc = b1[t];
  for (int i = 0; i < EV; ++i) acc += ef[i] * w1[i * H_DIM + t];

  red[t] = acc; __syncthreads();
  for (int s = 64; s > 0; s >>= 1) { if (t < s) red[t] += red[t + s]; __syncthreads(); }
  float mu = red[0] / H_DIM; __syncthreads();
  float d = acc - mu;
  red[t] = d * d; __syncthreads();
  for (int s = 64; s > 0; s >>= 1) { if (t < s) red[t] += red[t + s]; __syncthreads(); }
  float var = red[0] / H_DIM; __syncthreads();
  float y = d * rsqrtf(var + 1e-5f) * g1[t] + bt1[t];
  y = fmaxf(y, 0.f);
  sh[t] = y; __syncthreads();

  float acc2 = b2[t];
  for (int i = 0; i < H_DIM; ++i) acc2 += sh[i] * w2[i * H_DIM + t];

  red[t] = acc2; __syncthreads();
  for (int s = 64; s > 0; s >>= 1) { if (t < s) red[t] += red[t + s]; __syncthreads(); }
  mu = red[0] / H_DIM; __syncthreads();
  d = acc2 - mu;
  red[t] = d * d; __syncthreads();
  for (int s = 64; s > 0; s >>= 1) { if (t < s) red[t] += red[t + s]; __syncthreads(); }
  var = red[0] / H_DIM; __syncthreads();
  float y2 = d * rsqrtf(var + 1e-5f) * g2[t] + bt2[t];
  y2 = fmaxf(y2, 0.f);

  float m = 0.f;
  for (int k = 0; k < K; ++k) m += ett[etid[k] * H_DIM + t] * inten[k];
  e_out[t] = y2 + m / (float)K;
}

// ---------------------------------------------------------------------------
__global__ __launch_bounds__(256) void k_cvec_all(
    const float* __restrict__ e,
    const float* __restrict__ wq, const float* __restrict__ bq,
    const float* __restrict__ wk, const float* __restrict__ bk,
    const float* __restrict__ wv, const float* __restrict__ bv,
    const float* __restrict__ wskip, const float* __restrict__ bskip,
    const float* __restrict__ bih, const float* __restrict__ bhh,
    float* __restrict__ cvec1, float* __restrict__ cvec2)
{
  __shared__ float es[H_DIM];
  const int t = threadIdx.x;
  if (t < H_DIM) es[t] = e[t];
  __syncthreads();
  int j = blockIdx.x * 256 + t;
  if (j < 1664) {
    const float* W; const float* b; int col; int stride;
    if (j < 512)       { W = wq;    b = bq;    col = j;        stride = 512; }
    else if (j < 1024) { W = wk;    b = bk;    col = j - 512;  stride = 512; }
    else if (j < 1536) { W = wv;    b = bv;    col = j - 1024; stride = 512; }
    else               { W = wskip; b = bskip; col = j - 1536; stride = 128; }
    float a = b[col];
    for (int i = 0; i < H_DIM; ++i) a += es[i] * W[(D_DIM + i) * stride + col];
    cvec1[j] = a;
  } else if (j < 1664 + 384) {
    int j2 = j - 1664;
    int src = (j2 < 128) ? j2 : j2 + 128;   // i | g | o
    cvec2[j2] = bih[src] + bhh[src];
  }
}

// ---------------------------------------------------------------------------
__global__ __launch_bounds__(256) void k_split_all(
    const float* __restrict__ wq, const float* __restrict__ wk,
    const float* __restrict__ wv, const float* __restrict__ wskip,
    const float* __restrict__ g0w, const float* __restrict__ g1w,
    const float* __restrict__ wih,
    u16* __restrict__ hi, u16* __restrict__ lo)
{
  int idx = blockIdx.x * 256 + threadIdx.x;  // n*16 + g
  if (idx >= BCOL_TOT * 16) return;
  int n = idx >> 4, g = idx & 15;
  const float* W; int col, stride;
  if (n < 512)        { W = wq;    col = n;        stride = 512; }
  else if (n < 1024)  { W = wk;    col = n - 512;  stride = 512; }
  else if (n < 1536)  { W = wv;    col = n - 1024; stride = 512; }
  else if (n < 1664)  { W = wskip; col = n - 1536; stride = 128; }
  else if (n < 2176)  { W = g0w;   col = n - 1664; stride = 512; }
  else if (n < 2688)  { W = g1w;   col = n - 2176; stride = 512; }
  else { int c = n - 2688; W = wih; col = (c < 128) ? c : c + 128; stride = 512; }
  size_t dst = (size_t)(n >> 4) * 2048 + g * 128 + (n & 15) * 8;
#pragma unroll
  for (int j = 0; j < 8; ++j) {
    u16 h, l;
    split_bf16(W[(size_t)(g * 8 + j) * stride + col], h, l);
    hi[dst + j] = h; lo[dst + j] = l;
  }
}

// ---------------------------------------------------------------------------
__global__ __launch_bounds__(256) void k_split_a(
    const float* __restrict__ A, const int* __restrict__ ids,
    u16* __restrict__ hi, u16* __restrict__ lo, int M, int Mpad)
{
  int idx = blockIdx.x * 256 + threadIdx.x;   // row*16 + g
  if (idx >= Mpad * 16) return;
  int row = idx >> 4, g = idx & 15;
  size_t dst = (size_t)(row >> 4) * 2048 + g * 128 + (row & 15) * 8;
  if (row < M) {
    int ar = ids ? ids[row] : row;
    const float* srcp = A + (size_t)ar * 128 + g * 8;
#pragma unroll
    for (int j = 0; j < 8; ++j) {
      u16 h, l;
      split_bf16(srcp[j], h, l);
      hi[dst + j] = h; lo[dst + j] = l;
    }
  } else {
#pragma unroll
    for (int j = 0; j < 8; ++j) { hi[dst + j] = 0; lo[dst + j] = 0; }
  }
}

// ---------------------------------------------------------------------------
// Split-bf16 MFMA GEMM, NO LDS staging, NO barriers (FM operand layout).
// ---------------------------------------------------------------------------
__global__ __launch_bounds__(256, 3) void mfma_gemm(
    const u16* __restrict__ Ahi, const u16* __restrict__ Alo,
    const u16* __restrict__ Bhi, const u16* __restrict__ Blo,
    const float* __restrict__ cvec,
    u16* __restrict__ bf_out, int bf_cols,
    float* __restrict__ f32_out, int f32_lo, int ld_f32,
    const float* __restrict__ asw, const float* __restrict__ adw,
    float* __restrict__ a_s, float* __restrict__ a_d,
    int M)
{
  __shared__ float red[256];   // only used when asw != nullptr

  const int t = threadIdx.x;
  const int bm = blockIdx.y * 128;
  const int bn = blockIdx.x * 128;
  const int lane = t & 63;
  const int wid = t >> 6;
  const int wr = wid >> 1, wc = wid & 1;
  const int lg = lane >> 4;
  const int lr = lane & 15;

  const int arb = (bm >> 4) + wr * 4;
  const int brb = (bn >> 4) + wc * 4;

  f32x4 acc[4][4];
  const f32x4 zero = {0.f, 0.f, 0.f, 0.f};
#pragma unroll
  for (int i = 0; i < 4; ++i)
#pragma unroll
    for (int j = 0; j < 4; ++j) acc[i][j] = zero;

#pragma unroll
  for (int ks = 0; ks < 4; ++ks) {
    const int g = ks * 4 + lg;
    bf16x8 ah[4], al[4], bh[4], bl[4];
#pragma unroll
    for (int i = 0; i < 4; ++i) {
      size_t oa = (size_t)(arb + i) * 2048 + g * 128 + lr * 8;
      ah[i] = *(const bf16x8*)&Ahi[oa];
      al[i] = *(const bf16x8*)&Alo[oa];
      size_t ob = (size_t)(brb + i) * 2048 + g * 128 + lr * 8;
      bh[i] = *(const bf16x8*)&Bhi[ob];
      bl[i] = *(const bf16x8*)&Blo[ob];
    }
#pragma unroll
    for (int i = 0; i < 4; ++i)
#pragma unroll
      for (int j = 0; j < 4; ++j) {
        acc[i][j] = __builtin_amdgcn_mfma_f32_16x16x32_bf16(ah[i], bh[j], acc[i][j], 0, 0, 0);
        acc[i][j] = __builtin_amdgcn_mfma_f32_16x16x32_bf16(ah[i], bl[j], acc[i][j], 0, 0, 0);
        acc[i][j] = __builtin_amdgcn_mfma_f32_16x16x32_bf16(al[i], bh[j], acc[i][j], 0, 0, 0);
      }
  }

  const int rq = (lane >> 4) << 2;
  const int cq = lane & 15;
  const int head = bn >> 7;

  float ws_[4], wd_[4];
  if (asw) {
#pragma unroll
    for (int j = 0; j < 4; ++j) {
      int cc = (wc * 64 + j * 16 + cq) & 127;
      ws_[j] = asw[head * 128 + cc];
      wd_[j] = adw[head * 128 + cc];
    }
    if (t < 256) red[t] = 0.f;
    __syncthreads();
  }

#pragma unroll
  for (int i = 0; i < 4; ++i) {
#pragma unroll
    for (int r = 0; r < 4; ++r) {
      int rowl = wr * 64 + i * 16 + rq + r;
      int row = bm + rowl;
      bool rok = row < M;
      float ps = 0.f, pd = 0.f;
#pragma unroll
      for (int j = 0; j < 4; ++j) {
        int col = bn + wc * 64 + j * 16 + cq;
        float a = acc[i][j][r];
        if (rok) {
          float val = a + (cvec ? cvec[col] : 0.f);
          if (bf_out && col < bf_cols)
            bf_out[(size_t)row * bf_cols + col] =
                __builtin_bit_cast(u16, (__bf16)val);
          if (f32_out && col >= f32_lo)
            f32_out[(size_t)row * ld_f32 + (col - f32_lo)] = val;
        }
        if (asw) { ps += a * ws_[j]; pd += a * wd_[j]; }
      }
      if (asw && rok) {
        atomicAdd(&red[rowl], ps);
        atomicAdd(&red[128 + rowl], pd);
      }
    }
  }
  if (asw) {
    __syncthreads();
    if (t < 128) {
      int row = bm + t;
      if (row < M) {
        a_s[row * 4 + head] = red[t];
        a_d[row * 4 + head] = red[128 + t];
      }
    }
  }
}

// ---------------------------------------------------------------------------
__global__ __launch_bounds__(256) void k_zero(int* __restrict__ p, int n) {
  int i = blockIdx.x * 256 + threadIdx.x;
  if (i < n) p[i] = 0;
}
__global__ __launch_bounds__(256) void k_count(
    const int* __restrict__ dst, int* __restrict__ counts, int E) {
  int e = blockIdx.x * 256 + threadIdx.x;
  if (e < E) atomicAdd(&counts[dst[e]], 1);
}
__global__ __launch_bounds__(1024) void k_scan(
    const int* __restrict__ counts, int* __restrict__ offs,
    int* __restrict__ cursor, int N)
{
  __shared__ int wsum[16];
  const int t = threadIdx.x;
  const int lane = t & 63;
  const int wid = t >> 6;
  int running = 0;
  for (int base = 0; base < N; base += 1024) {
    int v = (base + t < N) ? counts[base + t] : 0;
    int incl = v;
#pragma unroll
    for (int s = 1; s < 64; s <<= 1) {
      int u = __shfl_up(incl, s);
      if (lane >= s) incl += u;
    }
    if (lane == 63) wsum[wid] = incl;
    __syncthreads();
    if (wid == 0) {
      int w = (lane < 16) ? wsum[lane] : 0;
#pragma unroll
      for (int s = 1; s < 16; s <<= 1) {
        int u = __shfl_up(w, s);
        if (lane >= s) w += u;
      }
      if (lane < 16) wsum[lane] = w;
    }
    __syncthreads();
    int wpre = (wid > 0) ? wsum[wid - 1] : 0;
    int tot = wsum[15];
    int inclg = incl + wpre;
    if (base + t < N) {
      offs[base + t + 1] = running + inclg;
      cursor[base + t] = running + inclg - v;
    }
    running += tot;
    __syncthreads();
  }
  if (t == 0) offs[0] = 0;
}
__global__ __launch_bounds__(256) void k_fill(
    const int* __restrict__ src, const int* __restrict__ dst,
    int* __restrict__ cursor, int* __restrict__ csr_src, int E) {
  int e = blockIdx.x * 256 + threadIdx.x;
  if (e < E) {
    int slot = atomicAdd(&cursor[dst[e]], 1);
    csr_src[slot] = src[e];
  }
}

// ---------------------------------------------------------------------------
// TransformerConv aggregation, ONLINE softmax, 4-edge unrolled, PERSISTENT
// waves with atomic work stealing (no tail). Straight-line rescale.
// q/K/V from bf16 panel QKVp[N][1536]; skip from fp32 skipbuf[N][128].
// Output: FM-layout hi/lo bf16 split.
// ---------------------------------------------------------------------------
__global__ __launch_bounds__(256) void k_tconv(
    const u16* __restrict__ QKVp, const float* __restrict__ skipbuf,
    const int* __restrict__ offs, const int* __restrict__ csr_src,
    u16* __restrict__ Xhi, u16* __restrict__ Xlo, int N, int Npad,
    int* __restrict__ wctr)
{
  const int lane = threadIdx.x & 63;

  for (;;) {
    const int node = steal(wctr, lane);
    if (node >= Npad) return;
    if (node >= N) {
      if (lane < 16) {
        size_t dst = (size_t)(node >> 4) * 2048 + lane * 128 + (node & 15) * 8;
#pragma unroll
        for (int j = 0; j < 8; ++j) { Xhi[dst + j] = 0; Xlo[dst + j] = 0; }
      }
      continue;
    }
    const u32x4 q = *(const u32x4*)(QKVp + (size_t)node * 1536 + lane * 8);

    const int beg = offs[node], end = offs[node + 1];
    float mx = -1e30f;
    float ssum = 0.f;
    f32x2 acc2[4];
#pragma unroll
    for (int jj = 0; jj < 4; ++jj) acc2[jj] = (f32x2){0.f, 0.f};

    int e = beg;
    for (; e + 4 <= end; e += 4) {
      int s0 = csr_src[e];
      int s1 = csr_src[e + 1];
      int s2 = csr_src[e + 2];
      int s3 = csr_src[e + 3];
      const u16* r0 = QKVp + (size_t)s0 * 1536 + 512 + lane * 8;
      const u16* r1 = QKVp + (size_t)s1 * 1536 + 512 + lane * 8;
      const u16* r2 = QKVp + (size_t)s2 * 1536 + 512 + lane * 8;
      const u16* r3 = QKVp + (size_t)s3 * 1536 + 512 + lane * 8;
      u32x4 k0 = *(const u32x4*)(r0);
      u32x4 k1 = *(const u32x4*)(r1);
      u32x4 k2 = *(const u32x4*)(r2);
      u32x4 k3 = *(const u32x4*)(r3);
      u32x4 v0 = *(const u32x4*)(r0 + 512);
      u32x4 v1 = *(const u32x4*)(r1 + 512);
      u32x4 v2 = *(const u32x4*)(r2 + 512);
      u32x4 v3 = *(const u32x4*)(r3 + 512);
      float p0 = qk_dot(q, k0);
      float p1 = qk_dot(q, k1);
      float p2 = qk_dot(q, k2);
      float p3 = qk_dot(q, k3);
      p0 = grp16_sum(p0) * SQRT_H_INV;
      p1 = grp16_sum(p1) * SQRT_H_INV;
      p2 = grp16_sum(p2) * SQRT_H_INV;
      p3 = grp16_sum(p3) * SQRT_H_INV;
      float nm = fmaxf(fmaxf(fmaxf(p0, p1), fmaxf(p2, p3)), mx);
      float sc = expf(mx - nm);
      float w0 = expf(p0 - nm);
      float w1 = expf(p1 - nm);
      float w2 = expf(p2 - nm);
      float w3 = expf(p3 - nm);
      ssum = ssum * sc + (w0 + w1) + (w2 + w3);
      f32x2 sc2 = {sc, sc};
      f32x2 w02 = {w0, w0}, w12 = {w1, w1}, w22 = {w2, w2}, w32 = {w3, w3};
#pragma unroll
      for (int jj = 0; jj < 4; ++jj)
        acc2[jj] = acc2[jj] * sc2 + (w02 * cvt2(v0[jj]) + w12 * cvt2(v1[jj]))
                                  + (w22 * cvt2(v2[jj]) + w32 * cvt2(v3[jj]));
      mx = nm;
    }
    for (; e < end; ++e) {
      int s0 = csr_src[e];
      const u16* r0 = QKVp + (size_t)s0 * 1536 + 512 + lane * 8;
      u32x4 k0 = *(const u32x4*)(r0);
      u32x4 v0 = *(const u32x4*)(r0 + 512);
      float p0 = qk_dot(q, k0);
      p0 = grp16_sum(p0) * SQRT_H_INV;
      float nm = fmaxf(mx, p0);
      float sc = expf(mx - nm);
      float w0 = expf(p0 - nm);
      ssum = ssum * sc + w0;
      f32x2 sc2 = {sc, sc};
      f32x2 w02 = {w0, w0};
#pragma unroll
      for (int jj = 0; jj < 4; ++jj)
        acc2[jj] = acc2[jj] * sc2 + w02 * cvt2(v0[jj]);
      mx = nm;
    }

    float inv = 1.f / (ssum + 1e-16f);
    float acc[8];
#pragma unroll
    for (int jj = 0; jj < 4; ++jj) {
      acc[jj * 2]     = acc2[jj][0] * inv;
      acc[jj * 2 + 1] = acc2[jj][1] * inv;
    }
#pragma unroll
    for (int j = 0; j < 8; ++j) {
      acc[j] += __shfl_xor(acc[j], 16);
      acc[j] += __shfl_xor(acc[j], 32);
    }
    if (lane < 16) {
      const float* sk = skipbuf + (size_t)node * 128 + lane * 8;
      size_t dst = (size_t)(node >> 4) * 2048 + lane * 128 + (node & 15) * 8;
#pragma unroll
      for (int j = 0; j < 8; ++j) {
        float x = 0.25f * acc[j] + sk[j];
        u16 h, l;
        split_bf16(x, h, l);
        Xhi[dst + j] = h; Xlo[dst + j] = l;
      }
    }
  }
}

// ---------------------------------------------------------------------------
// GAT aggregation, ONLINE softmax, 4-edge unrolled, PERSISTENT waves.
// Self + neighbors from bf16 panel xhb[N][512]; writes FM-layout split.
// ---------------------------------------------------------------------------
__global__ __launch_bounds__(256) void k_gat_agg(
    const u16* __restrict__ xhb,
    const float* __restrict__ a_s, const float* __restrict__ a_d,
    const int* __restrict__ offs, const int* __restrict__ csr_src,
    const float* __restrict__ bias,
    u16* __restrict__ Xhi, u16* __restrict__ Xlo, int N, int Npad,
    int* __restrict__ wctr)
{
  const int lane = threadIdx.x & 63;
  const int head = lane >> 4;

  for (;;) {
    const int node = steal(wctr, lane);
    if (node >= Npad) return;
    if (node >= N) {
      if (lane < 16) {
        size_t dst = (size_t)(node >> 4) * 2048 + lane * 128 + (node & 15) * 8;
#pragma unroll
        for (int j = 0; j < 8; ++j) { Xhi[dst + j] = 0; Xlo[dst + j] = 0; }
      }
      continue;
    }
    const float adn = a_d[node * 4 + head];
    const float asn = a_s[node * 4 + head];
    float lself = asn + adn;
    lself = lself >= 0.f ? lself : 0.2f * lself;

    float mx = lself;
    float ssum = 1.f;
    f32x2 acc2[4];
    {
      u32x4 xs = *(const u32x4*)(xhb + (size_t)node * 512 + lane * 8);
#pragma unroll
      for (int jj = 0; jj < 4; ++jj) acc2[jj] = cvt2(xs[jj]);
    }

    const int beg = offs[node], end = offs[node + 1];
    int e = beg;
    for (; e + 4 <= end; e += 4) {
      int s0 = csr_src[e];
      int s1 = csr_src[e + 1];
      int s2 = csr_src[e + 2];
      int s3 = csr_src[e + 3];
      float l0 = a_s[s0 * 4 + head];
      float l1 = a_s[s1 * 4 + head];
      float l2 = a_s[s2 * 4 + head];
      float l3 = a_s[s3 * 4 + head];
      const u16* r0 = xhb + (size_t)s0 * 512 + lane * 8;
      const u16* r1 = xhb + (size_t)s1 * 512 + lane * 8;
      const u16* r2 = xhb + (size_t)s2 * 512 + lane * 8;
      const u16* r3 = xhb + (size_t)s3 * 512 + lane * 8;
      u32x4 xa = *(const u32x4*)(r0);
      u32x4 xb = *(const u32x4*)(r1);
      u32x4 xc = *(const u32x4*)(r2);
      u32x4 xd = *(const u32x4*)(r3);
      l0 += adn; l1 += adn; l2 += adn; l3 += adn;
      l0 = l0 >= 0.f ? l0 : 0.2f * l0;
      l1 = l1 >= 0.f ? l1 : 0.2f * l1;
      l2 = l2 >= 0.f ? l2 : 0.2f * l2;
      l3 = l3 >= 0.f ? l3 : 0.2f * l3;
      float nm = fmaxf(fmaxf(fmaxf(l0, l1), fmaxf(l2, l3)), mx);
      float sc = expf(mx - nm);
      float w0 = expf(l0 - nm);
      float w1 = expf(l1 - nm);
      float w2 = expf(l2 - nm);
      float w3 = expf(l3 - nm);
      ssum = ssum * sc + (w0 + w1) + (w2 + w3);
      f32x2 sc2 = {sc, sc};
      f32x2 w02 = {w0, w0}, w12 = {w1, w1}, w22 = {w2, w2}, w32 = {w3, w3};
#pragma unroll
      for (int jj = 0; jj < 4; ++jj)
        acc2[jj] = acc2[jj] * sc2 + (w02 * cvt2(xa[jj]) + w12 * cvt2(xb[jj]))
                                  + (w22 * cvt2(xc[jj]) + w32 * cvt2(xd[jj]));
      mx = nm;
    }
    for (; e < end; ++e) {
      int s0 = csr_src[e];
      float l0 = a_s[s0 * 4 + head] + adn;
      l0 = l0 >= 0.f ? l0 : 0.2f * l0;
      const u16* r0 = xhb + (size_t)s0 * 512 + lane * 8;
      u32x4 xa = *(const u32x4*)(r0);
      float nm = fmaxf(mx, l0);
      float sc = expf(mx - nm);
      float w0 = expf(l0 - nm);
      ssum = ssum * sc + w0;
      f32x2 sc2 = {sc, sc};
      f32x2 w02 = {w0, w0};
#pragma unroll
      for (int jj = 0; jj < 4; ++jj)
        acc2[jj] = acc2[jj] * sc2 + w02 * cvt2(xa[jj]);
      mx = nm;
    }

    float inv = 1.f / (ssum + 1e-16f);
    float acc[8];
#pragma unroll
    for (int jj = 0; jj < 4; ++jj) {
      acc[jj * 2]     = acc2[jj][0] * inv;
      acc[jj * 2 + 1] = acc2[jj][1] * inv;
    }
#pragma unroll
    for (int j = 0; j < 8; ++j) {
      acc[j] += __shfl_xor(acc[j], 16);
      acc[j] += __shfl_xor(acc[j], 32);
    }
    if (lane < 16) {
      const float* b = bias + lane * 8;
      size_t dst = (size_t)(node >> 4) * 2048 + lane * 128 + (node & 15) * 8;
#pragma unroll
      for (int j = 0; j < 8; ++j) {
        float x = fmaxf(0.25f * acc[j] + b[j], 0.f);
        u16 h, l;
        split_bf16(x, h, l);
        Xhi[dst + j] = h; Xlo[dst + j] = l;
      }
    }
  }
}

// ---------------------------------------------------------------------------
__global__ __launch_bounds__(256) void k_lstm(
    const float* __restrict__ gates, float* __restrict__ out, int N)
{
  int idx = blockIdx.x * 256 + threadIdx.x;
  if (idx >= N * 128) return;
  int n = idx >> 7, c = idx & 127;
  const float* g = gates + (size_t)n * 384;
  float gi = g[c], gg = g[128 + c], go = g[256 + c];
  float cv = (1.f / (1.f + expf(-gi))) * tanhf(gg);
  float hv = (1.f / (1.f + expf(-go))) * tanhf(cv);
  out[idx] = hv;
  out[(size_t)N * 128 + idx] = cv;
}

// ---------------------------------------------------------------------------
extern "C" void kernel_launch(void* const* d_in, const int* in_sizes, int n_in,
                              void* d_out, int out_size, void* d_ws, size_t ws_size,
                              hipStream_t stream) {
  const int*   node_ids = (const int*)d_in[0];
  const int*   etid     = (const int*)d_in[1];
  const int*   src      = (const int*)d_in[2];
  const int*   dst      = (const int*)d_in[3];
  const float* ef       = (const float*)d_in[4];
  const float* inten    = (const float*)d_in[5];
  const float* nemb     = (const float*)d_in[6];
  const float* ett      = (const float*)d_in[7];
  const float* ev_w1 = (const float*)d_in[8],  *ev_b1 = (const float*)d_in[9];
  const float* ev_g1 = (const float*)d_in[10], *ev_bt1 = (const float*)d_in[11];
  const float* ev_w2 = (const float*)d_in[12], *ev_b2 = (const float*)d_in[13];
  const float* ev_g2 = (const float*)d_in[14], *ev_bt2 = (const float*)d_in[15];
  const float* wq = (const float*)d_in[16], *bq = (const float*)d_in[17];
  const float* wk = (const float*)d_in[18], *bk = (const float*)d_in[19];
  const float* wv = (const float*)d_in[20], *bv = (const float*)d_in[21];
  const float* wskip = (const float*)d_in[22], *bskip = (const float*)d_in[23];
  const float* g0_w = (const float*)d_in[24], *g0_as = (const float*)d_in[25];
  const float* g0_ad = (const float*)d_in[26], *g0_b = (const float*)d_in[27];
  const float* g1_w = (const float*)d_in[28], *g1_as = (const float*)d_in[29];
  const float* g1_ad = (const float*)d_in[30], *g1_b = (const float*)d_in[31];
  const float* wih = (const float*)d_in[32];
  const float* bih = (const float*)d_in[34], *bhh = (const float*)d_in[35];

  const int N = in_sizes[0];
  const int K = in_sizes[1];
  const int E = in_sizes[2];
  const int EV = in_sizes[4];

  const int gridMy = (N + 127) / 128;
  const int Npad = gridMy * 128;

  float* ws = (float*)d_ws;
  size_t o = 0;
  float* e_vec = ws + o; o += 128;
  float* cvec1 = ws + o; o += 1664;
  float* cvec2 = ws + o; o += 384;
  u16* Ballhi = (u16*)(ws + o); o += (size_t)BCOL_TOT * 64;
  u16* Balllo = (u16*)(ws + o); o += (size_t)BCOL_TOT * 64;
  u16* Ahi  = (u16*)(ws + o); o += (size_t)Npad * 64;
  u16* Alo  = (u16*)(ws + o); o += (size_t)Npad * 64;
  u16* XShi = (u16*)(ws + o); o += (size_t)Npad * 64;
  u16* XSlo = (u16*)(ws + o); o += (size_t)Npad * 64;
  u16* QKVp = (u16*)(ws + o); o += (size_t)Npad * 768;   // [N][1536] u16
  float* skipbuf = ws + o; o += (size_t)Npad * 128;
  u16* xhb  = (u16*)(ws + o); o += (size_t)Npad * 256;   // [N][512] u16
  float* gates = ws + o; o += (size_t)Npad * 192;        // [N][384] f32
  float* a_s   = ws + o; o += (size_t)N * 4;
  float* a_d   = ws + o; o += (size_t)N * 4;
  int* counts  = (int*)(ws + o); o += N;
  int* wctr    = (int*)(ws + o); o += 4;                 // work-steal counters
  int* offs    = (int*)(ws + o); o += (size_t)N + 1;
  int* cursor  = (int*)(ws + o); o += N;
  int* csr_src = (int*)(ws + o); o += E;

  float* out = (float*)d_out;
  const int persBlocks = 2048;   // 8192 waves = resident capacity

  k_event<<<1, 128, 0, stream>>>(ef, EV, ev_w1, ev_b1, ev_g1, ev_bt1,
                                 ev_w2, ev_b2, ev_g2, ev_bt2,
                                 ett, etid, inten, K, e_vec);
  k_cvec_all<<<8, 256, 0, stream>>>(e_vec, wq, bq, wk, bk, wv, bv,
                                    wskip, bskip, bih, bhh, cvec1, cvec2);
  k_split_all<<<(BCOL_TOT * 16) / 256, 256, 0, stream>>>(
      wq, wk, wv, wskip, g0_w, g1_w, wih, Ballhi, Balllo);
  k_split_a<<<(Npad * 16 + 255) / 256, 256, 0, stream>>>(nemb, node_ids, Ahi, Alo, N, Npad);

  // zero counts + the 4 work-steal counters (contiguous)
  k_zero<<<(N + 4 + 255) / 256, 256, 0, stream>>>(counts, N + 4);
  k_count<<<(E + 255) / 256, 256, 0, stream>>>(dst, counts, E);
  k_scan<<<1, 1024, 0, stream>>>(counts, offs, cursor, N);
  k_fill<<<(E + 255) / 256, 256, 0, stream>>>(src, dst, cursor, csr_src, E);

  // QKV: bf16 q|k|v -> QKVp; fp32 skip -> skipbuf
  mfma_gemm<<<dim3(13, gridMy), 256, 0, stream>>>(
      Ahi, Alo, Ballhi + (size_t)BCOL_QKV * 128, Balllo + (size_t)BCOL_QKV * 128,
      cvec1, QKVp, 1536, skipbuf, 1536, 128,
      nullptr, nullptr, nullptr, nullptr, N);

  k_tconv<<<persBlocks, 256, 0, stream>>>(QKVp, skipbuf, offs, csr_src,
                                          XShi, XSlo, N, Npad, &wctr[0]);

  // GAT layer 1: bf16 xhb + fused a_s/a_d
  mfma_gemm<<<dim3(4, gridMy), 256, 0, stream>>>(
      XShi, XSlo, Ballhi + (size_t)BCOL_G0 * 128, Balllo + (size_t)BCOL_G0 * 128,
      nullptr, xhb, 512, nullptr, 0, 0,
      g0_as, g0_ad, a_s, a_d, N);
  k_gat_agg<<<persBlocks, 256, 0, stream>>>(xhb, a_s, a_d, offs, csr_src,
                                            g0_b, XShi, XSlo, N, Npad, &wctr[1]);

  // GAT layer 2
  mfma_gemm<<<dim3(4, gridMy), 256, 0, stream>>>(
      XShi, XSlo, Ballhi + (size_t)BCOL_G1 * 128, Balllo + (size_t)BCOL_G1 * 128,
      nullptr, xhb, 512, nullptr, 0, 0,
      g1_as, g1_ad, a_s, a_d, N);
  k_gat_agg<<<persBlocks, 256, 0, stream>>>(xhb, a_s, a_d, offs, csr_src,
                                            g1_b, XShi, XSlo, N, Npad, &wctr[2]);

  // LSTM: fp32 gates (i,g,o) 384 wide
  mfma_gemm<<<dim3(3, gridMy), 256, 0, stream>>>(
      XShi, XSlo, Ballhi + (size_t)BCOL_W * 128, Balllo + (size_t)BCOL_W * 128,
      cvec2, nullptr, 0, gates, 0, 384,
      nullptr, nullptr, nullptr, nullptr, N);
  k_lstm<<<((N * 128) + 255) / 256, 256, 0, stream>>>(gates, out, N);
}

// Round 12
// 444.417 us; speedup vs baseline: 2.9276x; 2.9276x over previous
//
#include <hip/hip_runtime.h>
#include <math.h>

#define D_DIM 128
#define H_DIM 128
#define QKV_N 1664
#define SQRT_H_INV 0.08838834764831845f

typedef unsigned short u16;
typedef unsigned short ushort8v __attribute__((ext_vector_type(8)));
typedef __bf16 bf16x8 __attribute__((ext_vector_type(8)));
typedef float f32x4 __attribute__((ext_vector_type(4)));

__device__ __forceinline__ float grp16_sum(float v) {
  v += __shfl_xor(v, 1);
  v += __shfl_xor(v, 2);
  v += __shfl_xor(v, 4);
  v += __shfl_xor(v, 8);
  return v;
}

__device__ __forceinline__ void split_bf16(float x, u16& h, u16& l) {
  __bf16 hb = (__bf16)x;
  float rm = x - (float)hb;
  __bf16 lb = (__bf16)rm;
  h = __builtin_bit_cast(u16, hb);
  l = __builtin_bit_cast(u16, lb);
}

// ---------------------------------------------------------------------------
__global__ __launch_bounds__(128) void k_event(
    const float* __restrict__ ef, int EV,
    const float* __restrict__ w1, const float* __restrict__ b1,
    const float* __restrict__ g1, const float* __restrict__ bt1,
    const float* __restrict__ w2, const float* __restrict__ b2,
    const float* __restrict__ g2, const float* __restrict__ bt2,
    const float* __restrict__ ett, const int* __restrict__ etid,
    const float* __restrict__ inten, int K,
    float* __restrict__ e_out)
{
  __shared__ float sh[H_DIM];
  __shared__ float red[H_DIM];
  const int t = threadIdx.x;

  float acc = b1[t];
  for (int i = 0; i < EV; ++i) acc += ef[i] * w1[i * H_DIM + t];

  red[t] = acc; __syncthreads();
  for (int s = 64; s > 0; s >>= 1) { if (t < s) red[t] += red[t + s]; __syncthreads(); }
  float mu = red[0] / H_DIM; __syncthreads();
  float d = acc - mu;
  red[t] = d * d; __syncthreads();
  for (int s = 64; s > 0; s >>= 1) { if (t < s) red[t] += red[t + s]; __syncthreads(); }
  float var = red[0] / H_DIM; __syncthreads();
  float y = d * rsqrtf(var + 1e-5f) * g1[t] + bt1[t];
  y = fmaxf(y, 0.f);
  sh[t] = y; __syncthreads();

  float acc2 = b2[t];
  for (int i = 0; i < H_DIM; ++i) acc2 += sh[i] * w2[i * H_DIM + t];

  red[t] = acc2; __syncthreads();
  for (int s = 64; s > 0; s >>= 1) { if (t < s) red[t] += red[t + s]; __syncthreads(); }
  mu = red[0] / H_DIM; __syncthreads();
  d = acc2 - mu;
  red[t] = d * d; __syncthreads();
  for (int s = 64; s > 0; s >>= 1) { if (t < s) red[t] += red[t + s]; __syncthreads(); }
  var = red[0] / H_DIM; __syncthreads();
  float y2 = d * rsqrtf(var + 1e-5f) * g2[t] + bt2[t];
  y2 = fmaxf(y2, 0.f);

  float m = 0.f;
  for (int k = 0; k < K; ++k) m += ett[etid[k] * H_DIM + t] * inten[k];
  e_out[t] = y2 + m / (float)K;
}

// ---------------------------------------------------------------------------
__global__ __launch_bounds__(256) void k_cvec(
    const float* __restrict__ e,
    const float* __restrict__ wq, const float* __restrict__ bq,
    const float* __restrict__ wk, const float* __restrict__ bk,
    const float* __restrict__ wv, const float* __restrict__ bv,
    const float* __restrict__ wskip, const float* __restrict__ bskip,
    float* __restrict__ cvec)
{
  __shared__ float es[H_DIM];
  const int t = threadIdx.x;
  if (t < H_DIM) es[t] = e[t];
  __syncthreads();
  int j = blockIdx.x * 256 + t;
  if (j >= QKV_N) return;
  const float* W; const float* b; int col; int stride;
  if (j < 512)       { W = wq;    b = bq;    col = j;        stride = 512; }
  else if (j < 1024) { W = wk;    b = bk;    col = j - 512;  stride = 512; }
  else if (j < 1536) { W = wv;    b = bv;    col = j - 1024; stride = 512; }
  else               { W = wskip; b = bskip; col = j - 1536; stride = 128; }
  float a = b[col];
  for (int i = 0; i < H_DIM; ++i) a += es[i] * W[(D_DIM + i) * stride + col];
  cvec[j] = a;
}

__global__ __launch_bounds__(256) void k_pack(
    const float* __restrict__ wq, const float* __restrict__ wk,
    const float* __restrict__ wv, const float* __restrict__ wskip,
    float* __restrict__ B1)
{
  int idx = blockIdx.x * 256 + threadIdx.x;
  if (idx >= D_DIM * QKV_N) return;
  int i = idx / QKV_N, j = idx - i * QKV_N;
  float v;
  if (j < 512)       v = wq[i * 512 + j];
  else if (j < 1024) v = wk[i * 512 + (j - 512)];
  else if (j < 1536) v = wv[i * 512 + (j - 1024)];
  else               v = wskip[i * 128 + (j - 1536)];
  B1[idx] = v;
}

__global__ __launch_bounds__(256) void k_cvec2(
    const float* __restrict__ bih, const float* __restrict__ bhh,
    float* __restrict__ cvec2)
{
  int j = blockIdx.x * 256 + threadIdx.x;
  if (j < 512) cvec2[j] = bih[j] + bhh[j];
}

// ---------------------------------------------------------------------------
__global__ __launch_bounds__(256) void k_split_a(
    const float* __restrict__ A, const int* __restrict__ ids,
    u16* __restrict__ hi, u16* __restrict__ lo, int M, int Mpad)
{
  int idx = blockIdx.x * 256 + threadIdx.x;   // row*16 + g
  if (idx >= Mpad * 16) return;
  int row = idx >> 4, g = idx & 15;
  int gp = g ^ (row & 7);
  size_t dst = (size_t)row * 128 + gp * 8;
  if (row < M) {
    int ar = ids ? ids[row] : row;
    const float* srcp = A + (size_t)ar * 128 + g * 8;
#pragma unroll
    for (int j = 0; j < 8; ++j) {
      u16 h, l;
      split_bf16(srcp[j], h, l);
      hi[dst + j] = h; lo[dst + j] = l;
    }
  } else {
#pragma unroll
    for (int j = 0; j < 8; ++j) { hi[dst + j] = 0; lo[dst + j] = 0; }
  }
}

__global__ __launch_bounds__(256) void k_split_bt(
    const float* __restrict__ W,
    u16* __restrict__ hi, u16* __restrict__ lo, int Nc)
{
  int idx = blockIdx.x * 256 + threadIdx.x;  // n*16 + g
  if (idx >= Nc * 16) return;
  int n = idx >> 4, g = idx & 15;
  int gp = g ^ (n & 7);
  size_t dst = (size_t)n * 128 + gp * 8;
#pragma unroll
  for (int j = 0; j < 8; ++j) {
    u16 h, l;
    split_bf16(W[(size_t)(g * 8 + j) * Nc + n], h, l);
    hi[dst + j] = h; lo[dst + j] = l;
  }
}

// ---------------------------------------------------------------------------
// Split-bf16 MFMA GEMM, BK=64 two-phase, 64KB LDS (2 blocks/CU), with
// register prefetch of phase 1 overlapping phase-0 MFMAs.
// Epilogue: optional bf16 panel for cols [bf_lo,bf_hi); skipf32 drops the
// fp32 store in that range.
// ---------------------------------------------------------------------------
__global__ __launch_bounds__(256, 2) void mfma_gemm(
    const u16* __restrict__ Ahi, const u16* __restrict__ Alo,
    const u16* __restrict__ Bhi, const u16* __restrict__ Blo,
    const float* __restrict__ cvec, float* __restrict__ C, int M, int Nn,
    u16* __restrict__ bf_out, int bf_lo, int bf_hi, int bf_stride, int skipf32)
{
  __shared__ u16 lds[32768];   // 64 KB
  u16* As_hi = lds;
  u16* As_lo = lds + 8192;
  u16* Bs_hi = lds + 16384;
  u16* Bs_lo = lds + 24576;

  const int t = threadIdx.x;
  const int bm = blockIdx.y * 128;
  const int bn = blockIdx.x * 128;
  const int lane = t & 63;
  const int wid = t >> 6;
  const int wr = wid >> 1, wc = wid & 1;
  const int abase = wr * 64 + (lane & 15);
  const int bbase = wc * 64 + (lane & 15);

  int srow[4], sg[4];
#pragma unroll
  for (int i = 0; i < 4; ++i) {
    int idx = i * 256 + t;
    srow[i] = idx >> 3;
    sg[i] = idx & 7;
  }

  ushort8v ra_h[4], ra_l[4], rb_h[4], rb_l[4];

#pragma unroll
  for (int i = 0; i < 4; ++i) {
    size_t ga = (size_t)(bm + srow[i]) * 128 + sg[i] * 8;
    size_t gb = (size_t)(bn + srow[i]) * 128 + sg[i] * 8;
    ra_h[i] = *(const ushort8v*)&Ahi[ga];
    ra_l[i] = *(const ushort8v*)&Alo[ga];
    rb_h[i] = *(const ushort8v*)&Bhi[gb];
    rb_l[i] = *(const ushort8v*)&Blo[gb];
  }
#pragma unroll
  for (int i = 0; i < 4; ++i) {
    int lo_ = srow[i] * 64 + sg[i] * 8;
    *(ushort8v*)&As_hi[lo_] = ra_h[i];
    *(ushort8v*)&As_lo[lo_] = ra_l[i];
    *(ushort8v*)&Bs_hi[lo_] = rb_h[i];
    *(ushort8v*)&Bs_lo[lo_] = rb_l[i];
  }
  __syncthreads();

#pragma unroll
  for (int i = 0; i < 4; ++i) {
    size_t ga = (size_t)(bm + srow[i]) * 128 + 64 + sg[i] * 8;
    size_t gb = (size_t)(bn + srow[i]) * 128 + 64 + sg[i] * 8;
    ra_h[i] = *(const ushort8v*)&Ahi[ga];
    ra_l[i] = *(const ushort8v*)&Alo[ga];
    rb_h[i] = *(const ushort8v*)&Bhi[gb];
    rb_l[i] = *(const ushort8v*)&Blo[gb];
  }

  f32x4 acc[4][4];
  const f32x4 zero = {0.f, 0.f, 0.f, 0.f};
#pragma unroll
  for (int i = 0; i < 4; ++i)
#pragma unroll
    for (int j = 0; j < 4; ++j) acc[i][j] = zero;

#pragma unroll
  for (int ks = 0; ks < 2; ++ks) {
    const int gl = (((ks & 1) << 2) + (lane >> 4)) ^ (lane & 7);
    bf16x8 ah[4], al[4], bh[4], bl[4];
#pragma unroll
    for (int i = 0; i < 4; ++i) {
      int ra = (abase + i * 16) * 64 + gl * 8;
      ah[i] = *(const bf16x8*)&As_hi[ra];
      al[i] = *(const bf16x8*)&As_lo[ra];
      int rb = (bbase + i * 16) * 64 + gl * 8;
      bh[i] = *(const bf16x8*)&Bs_hi[rb];
      bl[i] = *(const bf16x8*)&Bs_lo[rb];
    }
#pragma unroll
    for (int i = 0; i < 4; ++i)
#pragma unroll
      for (int j = 0; j < 4; ++j) {
        acc[i][j] = __builtin_amdgcn_mfma_f32_16x16x32_bf16(ah[i], bh[j], acc[i][j], 0, 0, 0);
        acc[i][j] = __builtin_amdgcn_mfma_f32_16x16x32_bf16(ah[i], bl[j], acc[i][j], 0, 0, 0);
        acc[i][j] = __builtin_amdgcn_mfma_f32_16x16x32_bf16(al[i], bh[j], acc[i][j], 0, 0, 0);
      }
  }
  __syncthreads();

#pragma unroll
  for (int i = 0; i < 4; ++i) {
    int lo_ = srow[i] * 64 + sg[i] * 8;
    *(ushort8v*)&As_hi[lo_] = ra_h[i];
    *(ushort8v*)&As_lo[lo_] = ra_l[i];
    *(ushort8v*)&Bs_hi[lo_] = rb_h[i];
    *(ushort8v*)&Bs_lo[lo_] = rb_l[i];
  }
  __syncthreads();

#pragma unroll
  for (int ks = 2; ks < 4; ++ks) {
    const int gl = (((ks & 1) << 2) + (lane >> 4)) ^ (lane & 7);
    bf16x8 ah[4], al[4], bh[4], bl[4];
#pragma unroll
    for (int i = 0; i < 4; ++i) {
      int ra = (abase + i * 16) * 64 + gl * 8;
      ah[i] = *(const bf16x8*)&As_hi[ra];
      al[i] = *(const bf16x8*)&As_lo[ra];
      int rb = (bbase + i * 16) * 64 + gl * 8;
      bh[i] = *(const bf16x8*)&Bs_hi[rb];
      bl[i] = *(const bf16x8*)&Bs_lo[rb];
    }
#pragma unroll
    for (int i = 0; i < 4; ++i)
#pragma unroll
      for (int j = 0; j < 4; ++j) {
        acc[i][j] = __builtin_amdgcn_mfma_f32_16x16x32_bf16(ah[i], bh[j], acc[i][j], 0, 0, 0);
        acc[i][j] = __builtin_amdgcn_mfma_f32_16x16x32_bf16(ah[i], bl[j], acc[i][j], 0, 0, 0);
        acc[i][j] = __builtin_amdgcn_mfma_f32_16x16x32_bf16(al[i], bh[j], acc[i][j], 0, 0, 0);
      }
  }

  const int rq = (lane >> 4) << 2;
  const int cq = lane & 15;
#pragma unroll
  for (int j = 0; j < 4; ++j) {
    int col = bn + wc * 64 + j * 16 + cq;
    float cv = cvec ? cvec[col] : 0.f;
    bool inbf = bf_out && col >= bf_lo && col < bf_hi;
    bool wf32 = !(inbf && skipf32);
#pragma unroll
    for (int i = 0; i < 4; ++i) {
#pragma unroll
      for (int r = 0; r < 4; ++r) {
        int row = bm + wr * 64 + i * 16 + rq + r;
        if (row < M) {
          float val = acc[i][j][r] + cv;
          if (wf32) C[(size_t)row * Nn + col] = val;
          if (inbf) bf_out[(size_t)row * bf_stride + (col - bf_lo)] =
              __builtin_bit_cast(u16, (__bf16)val);
        }
      }
    }
  }
}

// ---------------------------------------------------------------------------
__global__ __launch_bounds__(256) void k_zero(int* __restrict__ p, int n) {
  int i = blockIdx.x * 256 + threadIdx.x;
  if (i < n) p[i] = 0;
}
__global__ __launch_bounds__(256) void k_count(
    const int* __restrict__ dst, int* __restrict__ counts, int E) {
  int e = blockIdx.x * 256 + threadIdx.x;
  if (e < E) atomicAdd(&counts[dst[e]], 1);
}
__global__ __launch_bounds__(1024) void k_scan(
    const int* __restrict__ counts, int* __restrict__ offs,
    int* __restrict__ cursor, int N)
{
  __shared__ int wsum[16];
  const int t = threadIdx.x;
  const int lane = t & 63;
  const int wid = t >> 6;
  int running = 0;
  for (int base = 0; base < N; base += 1024) {
    int v = (base + t < N) ? counts[base + t] : 0;
    int incl = v;
#pragma unroll
    for (int s = 1; s < 64; s <<= 1) {
      int u = __shfl_up(incl, s);
      if (lane >= s) incl += u;
    }
    if (lane == 63) wsum[wid] = incl;
    __syncthreads();
    if (wid == 0) {
      int w = (lane < 16) ? wsum[lane] : 0;
#pragma unroll
      for (int s = 1; s < 16; s <<= 1) {
        int u = __shfl_up(w, s);
        if (lane >= s) w += u;
      }
      if (lane < 16) wsum[lane] = w;
    }
    __syncthreads();
    int wpre = (wid > 0) ? wsum[wid - 1] : 0;
    int tot = wsum[15];
    int inclg = incl + wpre;
    if (base + t < N) {
      offs[base + t + 1] = running + inclg;
      cursor[base + t] = running + inclg - v;
    }
    running += tot;
    __syncthreads();
  }
  if (t == 0) offs[0] = 0;
}
__global__ __launch_bounds__(256) void k_fill(
    const int* __restrict__ src, const int* __restrict__ dst,
    int* __restrict__ cursor, int* __restrict__ csr_src, int E) {
  int e = blockIdx.x * 256 + threadIdx.x;
  if (e < E) {
    int slot = atomicAdd(&cursor[dst[e]], 1);
    csr_src[slot] = src[e];
  }
}

// ---------------------------------------------------------------------------
// TransformerConv aggregation, ONLINE softmax, 4-edge unrolled.
// Q/skip from fp32 C1 (stride 1664); K/V from bf16 panel KV[N][1024].
// ---------------------------------------------------------------------------
__global__ __launch_bounds__(256) void k_tconv(
    const float* __restrict__ C1, const u16* __restrict__ KV,
    const int* __restrict__ offs, const int* __restrict__ csr_src,
    u16* __restrict__ Xhi, u16* __restrict__ Xlo, int N)
{
  const int wid = threadIdx.x >> 6;
  const int lane = threadIdx.x & 63;
  const int node = blockIdx.x * 4 + wid;
  if (node >= N) {
    if (lane < 16) {
      size_t dst = (size_t)node * 128 + (size_t)((lane ^ (node & 7)) * 8);
#pragma unroll
      for (int j = 0; j < 8; ++j) { Xhi[dst + j] = 0; Xlo[dst + j] = 0; }
    }
    return;
  }
  const float* crow = C1 + (size_t)node * QKV_N;
  float q[8];
  {
    float4 q0 = *(const float4*)(crow + lane * 8);
    float4 q1 = *(const float4*)(crow + lane * 8 + 4);
    q[0]=q0.x; q[1]=q0.y; q[2]=q0.z; q[3]=q0.w;
    q[4]=q1.x; q[5]=q1.y; q[6]=q1.z; q[7]=q1.w;
  }
  const int beg = offs[node], end = offs[node + 1];
  float mx = -1e30f;
  float ssum = 0.f;
  float acc[8] = {0.f,0.f,0.f,0.f,0.f,0.f,0.f,0.f};

  int e = beg;
  for (; e + 4 <= end; e += 4) {
    int s0 = csr_src[e];
    int s1 = csr_src[e + 1];
    int s2 = csr_src[e + 2];
    int s3 = csr_src[e + 3];
    const u16* r0 = KV + (size_t)s0 * 1024 + lane * 8;
    const u16* r1 = KV + (size_t)s1 * 1024 + lane * 8;
    const u16* r2 = KV + (size_t)s2 * 1024 + lane * 8;
    const u16* r3 = KV + (size_t)s3 * 1024 + lane * 8;
    bf16x8 k0 = *(const bf16x8*)(r0);
    bf16x8 k1 = *(const bf16x8*)(r1);
    bf16x8 k2 = *(const bf16x8*)(r2);
    bf16x8 k3 = *(const bf16x8*)(r3);
    bf16x8 v0 = *(const bf16x8*)(r0 + 512);
    bf16x8 v1 = *(const bf16x8*)(r1 + 512);
    bf16x8 v2 = *(const bf16x8*)(r2 + 512);
    bf16x8 v3 = *(const bf16x8*)(r3 + 512);
    float p0 = 0.f, p1 = 0.f, p2 = 0.f, p3 = 0.f;
#pragma unroll
    for (int j = 0; j < 8; ++j) {
      p0 += q[j] * (float)k0[j];
      p1 += q[j] * (float)k1[j];
      p2 += q[j] * (float)k2[j];
      p3 += q[j] * (float)k3[j];
    }
    p0 = grp16_sum(p0) * SQRT_H_INV;
    p1 = grp16_sum(p1) * SQRT_H_INV;
    p2 = grp16_sum(p2) * SQRT_H_INV;
    p3 = grp16_sum(p3) * SQRT_H_INV;
    float nm = fmaxf(fmaxf(fmaxf(p0, p1), fmaxf(p2, p3)), mx);
    float sc = expf(mx - nm);
    float w0 = expf(p0 - nm);
    float w1 = expf(p1 - nm);
    float w2 = expf(p2 - nm);
    float w3 = expf(p3 - nm);
    ssum = ssum * sc + (w0 + w1) + (w2 + w3);
#pragma unroll
    for (int j = 0; j < 8; ++j)
      acc[j] = acc[j] * sc + (w0 * (float)v0[j] + w1 * (float)v1[j])
                           + (w2 * (float)v2[j] + w3 * (float)v3[j]);
    mx = nm;
  }
  for (; e < end; ++e) {
    int s0 = csr_src[e];
    const u16* r0 = KV + (size_t)s0 * 1024 + lane * 8;
    bf16x8 ka = *(const bf16x8*)(r0);
    bf16x8 va = *(const bf16x8*)(r0 + 512);
    float p0 = 0.f;
#pragma unroll
    for (int j = 0; j < 8; ++j) p0 += q[j] * (float)ka[j];
    p0 = grp16_sum(p0) * SQRT_H_INV;
    float nm = fmaxf(mx, p0);
    float sc = expf(mx - nm);
    float w0 = expf(p0 - nm);
    ssum = ssum * sc + w0;
#pragma unroll
    for (int j = 0; j < 8; ++j)
      acc[j] = acc[j] * sc + w0 * (float)va[j];
    mx = nm;
  }

  float inv = 1.f / (ssum + 1e-16f);
#pragma unroll
  for (int j = 0; j < 8; ++j) acc[j] *= inv;
#pragma unroll
  for (int j = 0; j < 8; ++j) {
    acc[j] += __shfl_xor(acc[j], 16);
    acc[j] += __shfl_xor(acc[j], 32);
  }
  if (lane < 16) {
    const float* sk = crow + 1536 + lane * 8;
    size_t dst = (size_t)node * 128 + (size_t)((lane ^ (node & 7)) * 8);
#pragma unroll
    for (int j = 0; j < 8; ++j) {
      float x = 0.25f * acc[j] + sk[j];
      u16 h, l;
      split_bf16(x, h, l);
      Xhi[dst + j] = h; Xlo[dst + j] = l;
    }
  }
}

// ---------------------------------------------------------------------------
__global__ __launch_bounds__(256) void k_gat_ad(
    const float* __restrict__ xh, const float* __restrict__ as_w,
    const float* __restrict__ ad_w, float* __restrict__ a_s,
    float* __restrict__ a_d, int N)
{
  const int wid = threadIdx.x >> 6;
  const int lane = threadIdx.x & 63;
  const int node = blockIdx.x * 4 + wid;
  if (node >= N) return;
  const int head = lane >> 4;
  const int c0 = (lane & 15) * 8;
  const float* xr = xh + (size_t)node * 512 + lane * 8;
  float4 x0 = *(const float4*)(xr);
  float4 x1_ = *(const float4*)(xr + 4);
  const float* aw = as_w + head * 128 + c0;
  const float* dw = ad_w + head * 128 + c0;
  float s1 = x0.x*aw[0] + x0.y*aw[1] + x0.z*aw[2] + x0.w*aw[3]
           + x1_.x*aw[4] + x1_.y*aw[5] + x1_.z*aw[6] + x1_.w*aw[7];
  float s2 = x0.x*dw[0] + x0.y*dw[1] + x0.z*dw[2] + x0.w*dw[3]
           + x1_.x*dw[4] + x1_.y*dw[5] + x1_.z*dw[6] + x1_.w*dw[7];
  s1 = grp16_sum(s1);
  s2 = grp16_sum(s2);
  if ((lane & 15) == 0) {
    a_s[node * 4 + head] = s1;
    a_d[node * 4 + head] = s2;
  }
}

// ---------------------------------------------------------------------------
// GAT aggregation, ONLINE softmax, 4-edge unrolled; self from fp32 xh,
// neighbors from bf16 panel xhb[N][512]; writes split hi/lo bf16.
// ---------------------------------------------------------------------------
__global__ __launch_bounds__(256) void k_gat_agg(
    const float* __restrict__ xh, const u16* __restrict__ xhb,
    const float* __restrict__ a_s, const float* __restrict__ a_d,
    const int* __restrict__ offs, const int* __restrict__ csr_src,
    const float* __restrict__ bias,
    u16* __restrict__ Xhi, u16* __restrict__ Xlo, int N)
{
  const int wid = threadIdx.x >> 6;
  const int lane = threadIdx.x & 63;
  const int node = blockIdx.x * 4 + wid;
  if (node >= N) {
    if (lane < 16) {
      size_t dst = (size_t)node * 128 + (size_t)((lane ^ (node & 7)) * 8);
#pragma unroll
      for (int j = 0; j < 8; ++j) { Xhi[dst + j] = 0; Xlo[dst + j] = 0; }
    }
    return;
  }
  const int head = lane >> 4;
  const float adn = a_d[node * 4 + head];
  const float asn = a_s[node * 4 + head];
  float lself = asn + adn;
  lself = lself >= 0.f ? lself : 0.2f * lself;

  float mx = lself;
  float ssum = 1.f;
  float acc[8];
  {
    const float* xr = xh + (size_t)node * 512 + lane * 8;
    float4 x0 = *(const float4*)(xr);
    float4 x1_ = *(const float4*)(xr + 4);
    acc[0]=x0.x; acc[1]=x0.y; acc[2]=x0.z; acc[3]=x0.w;
    acc[4]=x1_.x; acc[5]=x1_.y; acc[6]=x1_.z; acc[7]=x1_.w;
  }

  const int beg = offs[node], end = offs[node + 1];
  int e = beg;
  for (; e + 4 <= end; e += 4) {
    int s0 = csr_src[e];
    int s1 = csr_src[e + 1];
    int s2 = csr_src[e + 2];
    int s3 = csr_src[e + 3];
    float l0 = a_s[s0 * 4 + head];
    float l1 = a_s[s1 * 4 + head];
    float l2 = a_s[s2 * 4 + head];
    float l3 = a_s[s3 * 4 + head];
    const u16* r0 = xhb + (size_t)s0 * 512 + lane * 8;
    const u16* r1 = xhb + (size_t)s1 * 512 + lane * 8;
    const u16* r2 = xhb + (size_t)s2 * 512 + lane * 8;
    const u16* r3 = xhb + (size_t)s3 * 512 + lane * 8;
    bf16x8 xa = *(const bf16x8*)(r0);
    bf16x8 xb = *(const bf16x8*)(r1);
    bf16x8 xc = *(const bf16x8*)(r2);
    bf16x8 xd = *(const bf16x8*)(r3);
    l0 += adn; l1 += adn; l2 += adn; l3 += adn;
    l0 = l0 >= 0.f ? l0 : 0.2f * l0;
    l1 = l1 >= 0.f ? l1 : 0.2f * l1;
    l2 = l2 >= 0.f ? l2 : 0.2f * l2;
    l3 = l3 >= 0.f ? l3 : 0.2f * l3;
    float nm = fmaxf(fmaxf(fmaxf(l0, l1), fmaxf(l2, l3)), mx);
    float sc = expf(mx - nm);
    float w0 = expf(l0 - nm);
    float w1 = expf(l1 - nm);
    float w2 = expf(l2 - nm);
    float w3 = expf(l3 - nm);
    ssum = ssum * sc + (w0 + w1) + (w2 + w3);
#pragma unroll
    for (int j = 0; j < 8; ++j)
      acc[j] = acc[j] * sc + (w0 * (float)xa[j] + w1 * (float)xb[j])
                           + (w2 * (float)xc[j] + w3 * (float)xd[j]);
    mx = nm;
  }
  for (; e < end; ++e) {
    int s0 = csr_src[e];
    float l0 = a_s[s0 * 4 + head] + adn;
    l0 = l0 >= 0.f ? l0 : 0.2f * l0;
    const u16* r0 = xhb + (size_t)s0 * 512 + lane * 8;
    bf16x8 xa = *(const bf16x8*)(r0);
    float nm = fmaxf(mx, l0);
    float sc = expf(mx - nm);
    float w0 = expf(l0 - nm);
    ssum = ssum * sc + w0;
#pragma unroll
    for (int j = 0; j < 8; ++j)
      acc[j] = acc[j] * sc + w0 * (float)xa[j];
    mx = nm;
  }

  float inv = 1.f / (ssum + 1e-16f);
#pragma unroll
  for (int j = 0; j < 8; ++j) acc[j] *= inv;
#pragma unroll
  for (int j = 0; j < 8; ++j) {
    acc[j] += __shfl_xor(acc[j], 16);
    acc[j] += __shfl_xor(acc[j], 32);
  }
  if (lane < 16) {
    const float* b = bias + lane * 8;
    size_t dst = (size_t)node * 128 + (size_t)((lane ^ (node & 7)) * 8);
#pragma unroll
    for (int j = 0; j < 8; ++j) {
      float x = fmaxf(0.25f * acc[j] + b[j], 0.f);
      u16 h, l;
      split_bf16(x, h, l);
      Xhi[dst + j] = h; Xlo[dst + j] = l;
    }
  }
}

// ---------------------------------------------------------------------------
__global__ __launch_bounds__(256) void k_lstm(
    const float* __restrict__ gates, float* __restrict__ out, int N)
{
  int idx = blockIdx.x * 256 + threadIdx.x;
  if (idx >= N * 128) return;
  int n = idx >> 7, c = idx & 127;
  const float* g = gates + (size_t)n * 512;
  float gi = g[c], gg = g[256 + c], go = g[384 + c];
  float cv = (1.f / (1.f + expf(-gi))) * tanhf(gg);
  float hv = (1.f / (1.f + expf(-go))) * tanhf(cv);
  out[idx] = hv;
  out[(size_t)N * 128 + idx] = cv;
}

// ---------------------------------------------------------------------------
extern "C" void kernel_launch(void* const* d_in, const int* in_sizes, int n_in,
                              void* d_out, int out_size, void* d_ws, size_t ws_size,
                              hipStream_t stream) {
  const int*   node_ids = (const int*)d_in[0];
  const int*   etid     = (const int*)d_in[1];
  const int*   src      = (const int*)d_in[2];
  const int*   dst      = (const int*)d_in[3];
  const float* ef       = (const float*)d_in[4];
  const float* inten    = (const float*)d_in[5];
  const float* nemb     = (const float*)d_in[6];
  const float* ett      = (const float*)d_in[7];
  const float* ev_w1 = (const float*)d_in[8],  *ev_b1 = (const float*)d_in[9];
  const float* ev_g1 = (const float*)d_in[10], *ev_bt1 = (const float*)d_in[11];
  const float* ev_w2 = (const float*)d_in[12], *ev_b2 = (const float*)d_in[13];
  const float* ev_g2 = (const float*)d_in[14], *ev_bt2 = (const float*)d_in[15];
  const float* wq = (const float*)d_in[16], *bq = (const float*)d_in[17];
  const float* wk = (const float*)d_in[18], *bk = (const float*)d_in[19];
  const float* wv = (const float*)d_in[20], *bv = (const float*)d_in[21];
  const float* wskip = (const float*)d_in[22], *bskip = (const float*)d_in[23];
  const float* g0_w = (const float*)d_in[24], *g0_as = (const float*)d_in[25];
  const float* g0_ad = (const float*)d_in[26], *g0_b = (const float*)d_in[27];
  const float* g1_w = (const float*)d_in[28], *g1_as = (const float*)d_in[29];
  const float* g1_ad = (const float*)d_in[30], *g1_b = (const float*)d_in[31];
  const float* wih = (const float*)d_in[32];
  const float* bih = (const float*)d_in[34], *bhh = (const float*)d_in[35];

  const int N = in_sizes[0];
  const int K = in_sizes[1];
  const int E = in_sizes[2];
  const int EV = in_sizes[4];

  const int gridMy = (N + 127) / 128;
  const int Npad = gridMy * 128;

  float* ws = (float*)d_ws;
  size_t o = 0;
  float* e_vec = ws + o; o += 128;
  float* cvec1 = ws + o; o += QKV_N;
  float* cvec2 = ws + o; o += 512;
  float* B1    = ws + o; o += (size_t)128 * QKV_N;
  float* C1    = ws + o; o += (size_t)N * QKV_N;
  float* xh    = ws + o; o += (size_t)N * 512;
  u16* Ahi  = (u16*)(ws + o); o += (size_t)Npad * 64;
  u16* Alo  = (u16*)(ws + o); o += (size_t)Npad * 64;
  u16* XShi = (u16*)(ws + o); o += (size_t)Npad * 64;
  u16* XSlo = (u16*)(ws + o); o += (size_t)Npad * 64;
  u16* Bqhi = (u16*)(ws + o); o += (size_t)QKV_N * 64;
  u16* Bqlo = (u16*)(ws + o); o += (size_t)QKV_N * 64;
  u16* Bg0hi = (u16*)(ws + o); o += 512 * 64;
  u16* Bg0lo = (u16*)(ws + o); o += 512 * 64;
  u16* Bg1hi = (u16*)(ws + o); o += 512 * 64;
  u16* Bg1lo = (u16*)(ws + o); o += 512 * 64;
  u16* Bwhi  = (u16*)(ws + o); o += 512 * 64;
  u16* Bwlo  = (u16*)(ws + o); o += 512 * 64;
  u16* KV   = (u16*)(ws + o); o += (size_t)Npad * 512;  // [N][1024] u16
  u16* xhb  = (u16*)(ws + o); o += (size_t)Npad * 256;  // [N][512] u16
  float* a_s   = ws + o; o += (size_t)N * 4;
  float* a_d   = ws + o; o += (size_t)N * 4;
  int* counts  = (int*)(ws + o); o += N;
  int* offs    = (int*)(ws + o); o += (size_t)N + 1;
  int* cursor  = (int*)(ws + o); o += N;
  int* csr_src = (int*)(ws + o); o += E;

  float* out = (float*)d_out;

  const int nodeBlocks = (N + 3) / 4;
  const int nodeBlocksPad = Npad / 4;

  k_event<<<1, 128, 0, stream>>>(ef, EV, ev_w1, ev_b1, ev_g1, ev_bt1,
                                 ev_w2, ev_b2, ev_g2, ev_bt2,
                                 ett, etid, inten, K, e_vec);
  k_cvec<<<(QKV_N + 255) / 256, 256, 0, stream>>>(e_vec, wq, bq, wk, bk, wv, bv,
                                                  wskip, bskip, cvec1);
  k_pack<<<(D_DIM * QKV_N + 255) / 256, 256, 0, stream>>>(wq, wk, wv, wskip, B1);
  k_cvec2<<<2, 256, 0, stream>>>(bih, bhh, cvec2);

  k_split_a<<<(Npad * 16 + 255) / 256, 256, 0, stream>>>(nemb, node_ids, Ahi, Alo, N, Npad);
  k_split_bt<<<(QKV_N * 16 + 255) / 256, 256, 0, stream>>>(B1, Bqhi, Bqlo, QKV_N);
  k_split_bt<<<(512 * 16 + 255) / 256, 256, 0, stream>>>(g0_w, Bg0hi, Bg0lo, 512);
  k_split_bt<<<(512 * 16 + 255) / 256, 256, 0, stream>>>(g1_w, Bg1hi, Bg1lo, 512);
  k_split_bt<<<(512 * 16 + 255) / 256, 256, 0, stream>>>(wih, Bwhi, Bwlo, 512);

  k_zero<<<(N + 255) / 256, 256, 0, stream>>>(counts, N);
  k_count<<<(E + 255) / 256, 256, 0, stream>>>(dst, counts, E);
  k_scan<<<1, 1024, 0, stream>>>(counts, offs, cursor, N);
  k_fill<<<(E + 255) / 256, 256, 0, stream>>>(src, dst, cursor, csr_src, E);

  // QKV: fp32 q/skip -> C1 (K/V cols skipped); bf16 K/V -> KV panel
  mfma_gemm<<<dim3(QKV_N / 128, gridMy), 256, 0, stream>>>(
      Ahi, Alo, Bqhi, Bqlo, cvec1, C1, N, QKV_N,
      KV, 512, 1536, 1024, 1);

  k_tconv<<<nodeBlocksPad, 256, 0, stream>>>(C1, KV, offs, csr_src, XShi, XSlo, N);

  // GAT layer 1: fp32 xh + bf16 xhb
  mfma_gemm<<<dim3(4, gridMy), 256, 0, stream>>>(
      XShi, XSlo, Bg0hi, Bg0lo, nullptr, xh, N, 512,
      xhb, 0, 512, 512, 0);
  k_gat_ad<<<nodeBlocks, 256, 0, stream>>>(xh, g0_as, g0_ad, a_s, a_d, N);
  k_gat_agg<<<nodeBlocksPad, 256, 0, stream>>>(xh, xhb, a_s, a_d, offs, csr_src,
                                               g0_b, XShi, XSlo, N);

  // GAT layer 2
  mfma_gemm<<<dim3(4, gridMy), 256, 0, stream>>>(
      XShi, XSlo, Bg1hi, Bg1lo, nullptr, xh, N, 512,
      xhb, 0, 512, 512, 0);
  k_gat_ad<<<nodeBlocks, 256, 0, stream>>>(xh, g1_as, g1_ad, a_s, a_d, N);
  k_gat_agg<<<nodeBlocksPad, 256, 0, stream>>>(xh, xhb, a_s, a_d, offs, csr_src,
                                               g1_b, XShi, XSlo, N);

  // LSTM
  mfma_gemm<<<dim3(4, gridMy), 256, 0, stream>>>(
      XShi, XSlo, Bwhi, Bwlo, cvec2, xh, N, 512,
      nullptr, 0, 0, 0, 0);
  k_lstm<<<((N * 128) + 255) / 256, 256, 0, stream>>>(xh, out, N);
}